// Round 4
// baseline (163.165 us; speedup 1.0000x reference)
//
#include <hip/hip_runtime.h>
#include <hip/hip_cooperative_groups.h>

namespace cg = cooperative_groups;

typedef float f32x2 __attribute__((ext_vector_type(2)));

#define B     32
#define C     256
#define CS    64
#define HW    3136
#define HW4   784
#define HWF2  1568      // HW in float2
#define EPS   1e-5f
#define NBLK  512
#define NTHR  512
#define VPT   49        // float2 per thread (49*32 = 1568)

static __device__ __forceinline__ unsigned pack_bf16(float a, float b) {
    unsigned ua = __float_as_uint(a);
    unsigned ub = __float_as_uint(b);
    ua += 0x7FFFu + ((ua >> 16) & 1u);   // round-to-nearest-even
    ub += 0x7FFFu + ((ub >> 16) & 1u);
    return (ua >> 16) | (ub & 0xFFFF0000u);
}
static __device__ __forceinline__ float2 unpack_bf16(unsigned p) {
    return make_float2(__uint_as_float(p << 16),
                       __uint_as_float(p & 0xFFFF0000u));
}

// ---------------- Fused cooperative kernel ----------------
// 512 blocks x 512 threads. Each 32-lane group owns one (b,c) plane.
// Phase 1: pool (x cached in regs as packed bf16). Phase 2: MLP on blocks
// 0..31. Phase 3: pure-write excite from the register cache.
__global__ __launch_bounds__(NTHR, 4) void se_fused(
        const float* __restrict__ x,
        const float* __restrict__ w1,
        const float* __restrict__ bn1_gamma, const float* __restrict__ bn1_beta,
        const float* __restrict__ bn1_mean,  const float* __restrict__ bn1_var,
        const float* __restrict__ w2,
        const float* __restrict__ bn2_gamma, const float* __restrict__ bn2_beta,
        const float* __restrict__ bn2_mean,  const float* __restrict__ bn2_var,
        float* __restrict__ out,
        float* __restrict__ s,
        float* __restrict__ g) {
    cg::grid_group grid = cg::this_grid();

    const int T  = blockIdx.x * NTHR + threadIdx.x;
    const int bc = T >> 5;          // 0..8191
    const int r  = T & 31;

    const f32x2* __restrict__ xp = (const f32x2*)x + (size_t)bc * HWF2 + r;

    // ---- Phase 1: load slice, pool in fp32, cache as bf16x2 ----
    unsigned v[VPT];
    float acc = 0.f;
    #pragma unroll
    for (int m = 0; m < VPT; ++m) {
        f32x2 t = xp[m * 32];
        acc += t.x + t.y;
        v[m] = pack_bf16(t.x, t.y);
    }
    #pragma unroll
    for (int off = 16; off; off >>= 1) acc += __shfl_xor(acc, off, 64);
    if (r == 0) s[bc] = acc * (1.0f / (float)HW);

    grid.sync();

    // ---- Phase 2: MLP on blocks 0..31 (b = blockIdx.x) ----
    __shared__ float s_lds[C];
    __shared__ float h_lds[CS];
    if (blockIdx.x < B) {
        const int t = threadIdx.x;
        if (t < C) s_lds[t] = s[blockIdx.x * C + t];
        __syncthreads();
        if (t < C) {
            const int cs = t >> 2, j = t & 3;  // 4 threads per h-output
            const float4* wp = (const float4*)(w1 + cs * C) + j * 16;
            const float*  sp = s_lds + j * 64;
            float p = 0.f;
            #pragma unroll
            for (int k = 0; k < 16; ++k) {
                float4 w = wp[k];
                p += w.x * sp[4*k] + w.y * sp[4*k+1] + w.z * sp[4*k+2] + w.w * sp[4*k+3];
            }
            p += __shfl_xor(p, 1, 64);
            p += __shfl_xor(p, 2, 64);
            if (j == 0) {
                const float sc = bn1_gamma[cs] * rsqrtf(bn1_var[cs] + EPS);
                h_lds[cs] = fmaxf((p - bn1_mean[cs]) * sc + bn1_beta[cs], 0.f);
            }
        }
        __syncthreads();
        if (t < C) {
            const float4* wp = (const float4*)(w2 + t * CS);
            float a = 0.f;
            #pragma unroll
            for (int k = 0; k < 16; ++k) {
                float4 w = wp[k];
                a += w.x * h_lds[4*k] + w.y * h_lds[4*k+1] + w.z * h_lds[4*k+2] + w.w * h_lds[4*k+3];
            }
            const float sc = bn2_gamma[t] * rsqrtf(bn2_var[t] + EPS);
            float gg = (a - bn2_mean[t]) * sc + bn2_beta[t];
            g[blockIdx.x * C + t] = fminf(fmaxf(gg + 3.f, 0.f), 6.f) * (1.0f / 6.0f);
        }
    }

    grid.sync();

    // ---- Phase 3: excite, pure write from register cache ----
    const float gv = g[bc];
    f32x2* __restrict__ op = (f32x2*)out + (size_t)bc * HWF2 + r;
    #pragma unroll
    for (int m = 0; m < VPT; ++m) {
        float2 f = unpack_bf16(v[m]);
        f32x2 o;
        o.x = f.x * gv;
        o.y = f.y * gv;
        __builtin_nontemporal_store(o, op + m * 32);
    }
}

// ================= Fallback path (proven R2 kernels) =================
__global__ __launch_bounds__(256) void se_pool(const float* __restrict__ x,
                                               float* __restrict__ s) {
    const int bc = blockIdx.x;
    const float4* xp = (const float4*)(x + (size_t)bc * HW);
    float sum = 0.f;
    for (int i = threadIdx.x; i < HW4; i += 256) {
        float4 v = xp[i];
        sum += (v.x + v.y) + (v.z + v.w);
    }
    for (int off = 32; off; off >>= 1) sum += __shfl_down(sum, off, 64);
    __shared__ float red[4];
    const int lane = threadIdx.x & 63;
    const int wid  = threadIdx.x >> 6;
    if (lane == 0) red[wid] = sum;
    __syncthreads();
    if (threadIdx.x == 0) {
        float t = (red[0] + red[1]) + (red[2] + red[3]);
        s[bc] = t * (1.0f / (float)HW);
    }
}

__global__ __launch_bounds__(256) void se_mlp1(
        const float* __restrict__ s, const float* __restrict__ w1,
        const float* __restrict__ bn1_gamma, const float* __restrict__ bn1_beta,
        const float* __restrict__ bn1_mean,  const float* __restrict__ bn1_var,
        float* __restrict__ h) {
    const int o    = blockIdx.x * 4 + (threadIdx.x >> 6);
    const int lane = threadIdx.x & 63;
    const int b  = o >> 6;
    const int cs = o & 63;
    const float* sp = s  + b  * C;
    const float* wp = w1 + cs * C;
    float acc = 0.f;
    #pragma unroll
    for (int k = 0; k < 4; ++k) {
        const int idx = lane + k * 64;
        acc += sp[idx] * wp[idx];
    }
    #pragma unroll
    for (int off = 32; off; off >>= 1) acc += __shfl_down(acc, off, 64);
    if (lane == 0) {
        const float scale = bn1_gamma[cs] * rsqrtf(bn1_var[cs] + EPS);
        float v = (acc - bn1_mean[cs]) * scale + bn1_beta[cs];
        h[o] = fmaxf(v, 0.f);
    }
}

__global__ __launch_bounds__(256) void se_mlp2(
        const float* __restrict__ h, const float* __restrict__ w2,
        const float* __restrict__ bn2_gamma, const float* __restrict__ bn2_beta,
        const float* __restrict__ bn2_mean,  const float* __restrict__ bn2_var,
        float* __restrict__ g) {
    __shared__ float hb[CS];
    const int b = blockIdx.x;
    const int c = threadIdx.x;
    if (c < CS) hb[c] = h[b * CS + c];
    __syncthreads();
    const float* wp = w2 + c * CS;
    float acc = 0.f;
    #pragma unroll
    for (int k = 0; k < CS; k += 4) {
        float4 wv = *(const float4*)(wp + k);
        acc += wv.x * hb[k] + wv.y * hb[k+1] + wv.z * hb[k+2] + wv.w * hb[k+3];
    }
    const float scale = bn2_gamma[c] * rsqrtf(bn2_var[c] + EPS);
    float v = (acc - bn2_mean[c]) * scale + bn2_beta[c];
    v = fminf(fmaxf(v + 3.f, 0.f), 6.f) * (1.f / 6.f);
    g[b * C + c] = v;
}

__global__ __launch_bounds__(256) void se_scale(const float* __restrict__ x,
                                                const float* __restrict__ g,
                                                float* __restrict__ out) {
    const unsigned total4 = (unsigned)B * C * HW4;
    for (unsigned i = blockIdx.x * 256u + threadIdx.x; i < total4;
         i += gridDim.x * 256u) {
        const unsigned bc = i / HW4;
        const float gv = g[bc];
        float4 v = ((const float4*)x)[i];
        v.x *= gv; v.y *= gv; v.z *= gv; v.w *= gv;
        ((float4*)out)[i] = v;
    }
}

extern "C" void kernel_launch(void* const* d_in, const int* in_sizes, int n_in,
                              void* d_out, int out_size, void* d_ws, size_t ws_size,
                              hipStream_t stream) {
    const float* x         = (const float*)d_in[0];
    const float* w1        = (const float*)d_in[1];
    const float* bn1_gamma = (const float*)d_in[2];
    const float* bn1_beta  = (const float*)d_in[3];
    const float* bn1_mean  = (const float*)d_in[4];
    const float* bn1_var   = (const float*)d_in[5];
    const float* w2        = (const float*)d_in[6];
    const float* bn2_gamma = (const float*)d_in[7];
    const float* bn2_beta  = (const float*)d_in[8];
    const float* bn2_mean  = (const float*)d_in[9];
    const float* bn2_var   = (const float*)d_in[10];
    float* out = (float*)d_out;

    float* s = (float*)d_ws;          // 8192 floats
    float* g = s + B * C;             // 8192 floats
    float* h = g + B * C;             // 2048 floats

    void* args[] = {
        (void*)&x, (void*)&w1,
        (void*)&bn1_gamma, (void*)&bn1_beta, (void*)&bn1_mean, (void*)&bn1_var,
        (void*)&w2,
        (void*)&bn2_gamma, (void*)&bn2_beta, (void*)&bn2_mean, (void*)&bn2_var,
        (void*)&out, (void*)&s, (void*)&g
    };
    hipError_t e = hipLaunchCooperativeKernel((const void*)se_fused,
                                              dim3(NBLK), dim3(NTHR),
                                              args, 0, stream);
    if (e != hipSuccess) {
        // Fallback: proven 4-kernel path.
        se_pool<<<B * C, 256, 0, stream>>>(x, s);
        se_mlp1<<<(B * CS) / 4, 256, 0, stream>>>(s, w1, bn1_gamma, bn1_beta,
                                                  bn1_mean, bn1_var, h);
        se_mlp2<<<B, 256, 0, stream>>>(h, w2, bn2_gamma, bn2_beta,
                                       bn2_mean, bn2_var, g);
        se_scale<<<2048, 256, 0, stream>>>(x, g, out);
    }
}

// Round 7
// 59.861 us; speedup vs baseline: 2.7257x; 2.7257x over previous
//
#include <hip/hip_runtime.h>

typedef float f32x4 __attribute__((ext_vector_type(4)));

#define B    32
#define C    256
#define CS   64
#define HW   3136
#define HW4  784
#define EPS  1e-5f

// ---------------- Kernel 1: global average pool ----------------
// One block per (b,c) plane. Normal (caching) loads: warms L3 for kernel 2.
__global__ __launch_bounds__(256) void se_pool(const float* __restrict__ x,
                                               float* __restrict__ s) {
    const int bc = blockIdx.x;  // 0..8191
    const float4* xp = (const float4*)(x + (size_t)bc * HW);
    float sum = 0.f;
    for (int i = threadIdx.x; i < HW4; i += 256) {
        float4 v = xp[i];
        sum += (v.x + v.y) + (v.z + v.w);
    }
    #pragma unroll
    for (int off = 32; off; off >>= 1) sum += __shfl_down(sum, off, 64);
    __shared__ float red[4];
    const int lane = threadIdx.x & 63;
    const int wid  = threadIdx.x >> 6;
    if (lane == 0) red[wid] = sum;
    __syncthreads();
    if (threadIdx.x == 0) {
        float t = (red[0] + red[1]) + (red[2] + red[3]);
        s[bc] = t * (1.0f / (float)HW);
    }
}

// ---------------- Kernel 2: fused MLP + excite ----------------
// Grid: 1024 blocks = (batch b) x (32 groups of 8 channels). Each block
// redundantly computes h[b,:] (32K MACs, ~free), then g for its 8 channels,
// then scales its 8 planes. x re-read hits L3; nontemporal stores keep x
// resident.
__global__ __launch_bounds__(256) void se_mlp_scale(
        const float* __restrict__ x,
        const float* __restrict__ s,
        const float* __restrict__ w1,
        const float* __restrict__ bn1_gamma, const float* __restrict__ bn1_beta,
        const float* __restrict__ bn1_mean,  const float* __restrict__ bn1_var,
        const float* __restrict__ w2,
        const float* __restrict__ bn2_gamma, const float* __restrict__ bn2_beta,
        const float* __restrict__ bn2_mean,  const float* __restrict__ bn2_var,
        float* __restrict__ out) {
    __shared__ float s_lds[C];
    __shared__ float h_lds[CS];
    __shared__ float g_lds[8];

    const int b  = blockIdx.x >> 5;   // batch row
    const int cg = blockIdx.x & 31;   // channel group (8 channels)
    const int t  = threadIdx.x;

    s_lds[t] = s[b * C + t];
    __syncthreads();

    // h[cs] = ReLU(BN1(dot(s, w1[cs,:]))) — 4 threads per output
    {
        const int cs = t >> 2, j = t & 3;
        const float4* wp = (const float4*)(w1 + cs * C) + j * 16;
        const float*  sp = s_lds + j * 64;
        float p = 0.f;
        #pragma unroll
        for (int k = 0; k < 16; ++k) {
            float4 w = wp[k];
            p += w.x * sp[4*k] + w.y * sp[4*k+1] + w.z * sp[4*k+2] + w.w * sp[4*k+3];
        }
        p += __shfl_xor(p, 1, 64);
        p += __shfl_xor(p, 2, 64);
        if (j == 0) {
            const float sc = bn1_gamma[cs] * rsqrtf(bn1_var[cs] + EPS);
            h_lds[cs] = fmaxf((p - bn1_mean[cs]) * sc + bn1_beta[cs], 0.f);
        }
    }
    __syncthreads();

    // g for this block's 8 channels — threads 0..31, 4 per output
    if (t < 32) {
        const int c = cg * 8 + (t >> 2), j = t & 3;
        const float4* wp = (const float4*)(w2 + c * CS) + j * 4;
        const float*  hp = h_lds + j * 16;
        float a = 0.f;
        #pragma unroll
        for (int k = 0; k < 4; ++k) {
            float4 w = wp[k];
            a += w.x * hp[4*k] + w.y * hp[4*k+1] + w.z * hp[4*k+2] + w.w * hp[4*k+3];
        }
        a += __shfl_xor(a, 1, 64);
        a += __shfl_xor(a, 2, 64);
        if (j == 0) {
            const float sc = bn2_gamma[c] * rsqrtf(bn2_var[c] + EPS);
            float gg = (a - bn2_mean[c]) * sc + bn2_beta[c];
            g_lds[t >> 2] = fminf(fmaxf(gg + 3.f, 0.f), 6.f) * (1.0f / 6.0f);
        }
    }
    __syncthreads();

    // Scale 8 contiguous planes: 8*784 = 6272 float4.
    const size_t base4 = (size_t)(b * C + cg * 8) * HW4;
    const f32x4* xp = (const f32x4*)x + base4;
    f32x4*       op = (f32x4*)out + base4;
    for (int i = t; i < 8 * HW4; i += 256) {
        const float gv = g_lds[i / HW4];
        f32x4 v = xp[i];
        v.x *= gv; v.y *= gv; v.z *= gv; v.w *= gv;
        __builtin_nontemporal_store(v, op + i);
    }
}

extern "C" void kernel_launch(void* const* d_in, const int* in_sizes, int n_in,
                              void* d_out, int out_size, void* d_ws, size_t ws_size,
                              hipStream_t stream) {
    const float* x         = (const float*)d_in[0];
    const float* w1        = (const float*)d_in[1];
    const float* bn1_gamma = (const float*)d_in[2];
    const float* bn1_beta  = (const float*)d_in[3];
    const float* bn1_mean  = (const float*)d_in[4];
    const float* bn1_var   = (const float*)d_in[5];
    const float* w2        = (const float*)d_in[6];
    const float* bn2_gamma = (const float*)d_in[7];
    const float* bn2_beta  = (const float*)d_in[8];
    const float* bn2_mean  = (const float*)d_in[9];
    const float* bn2_var   = (const float*)d_in[10];
    float* out = (float*)d_out;

    float* s = (float*)d_ws;          // 8192 floats

    se_pool<<<B * C, 256, 0, stream>>>(x, s);
    se_mlp_scale<<<B * 32, 256, 0, stream>>>(x, s, w1,
                                             bn1_gamma, bn1_beta, bn1_mean, bn1_var,
                                             w2,
                                             bn2_gamma, bn2_beta, bn2_mean, bn2_var,
                                             out);
}